// Round 2
// baseline (1748.482 us; speedup 1.0000x reference)
//
#include <hip/hip_runtime.h>

// SparseConv3d(32->64, k=3, s=2, p=1), (21,800,704) grid, nnz=220939.
// Output-major GATHER: dense int32 index grid in d_ws (+ linked list for
// duplicate coords), one wave per output site (lane=cout). No atomics on the
// output, zeroing fused into the coalesced store.

#define CIN  32
#define COUT 64
#define IXD  21
#define IYD  800
#define IZD  704
#define OXD  11
#define OYD  400
#define OZD  352
#define NSITES (OXD * OYD * OZD)   // 1,548,800
#define NCELLS (IXD * IYD * IZD)   // 11,827,200

__global__ __launch_bounds__(256) void zero_grid(int* __restrict__ g) {
    int4* p = (int4*)g;
    const int i = blockIdx.x * 256 + threadIdx.x;
    const int n4 = NCELLS / 4;           // 2,956,800 (exact)
    if (i < n4) p[i] = make_int4(0, 0, 0, 0);
}

__global__ __launch_bounds__(256) void build_grid(
    const int* __restrict__ coords, int* __restrict__ g,
    int* __restrict__ nxt, int nnz)
{
    const int n = blockIdx.x * 256 + threadIdx.x;
    if (n >= nnz) return;
    const int cx = coords[3 * n + 0];
    const int cy = coords[3 * n + 1];
    const int cz = coords[3 * n + 2];
    const int flat = (cx * IYD + cy) * IZD + cz;
    const int old = atomicExch(&g[flat], n + 1);   // head insert; 0 = empty
    nxt[n] = old;
}

__global__ __launch_bounds__(256) void spconv_gather(
    const float* __restrict__ feat,
    const float* __restrict__ weight,
    const int*   __restrict__ g,
    const int*   __restrict__ nxt,
    float*       __restrict__ out)
{
    const int lane = threadIdx.x & 63;
    int site = blockIdx.x * 4 + (threadIdx.x >> 6);
    site = __builtin_amdgcn_readfirstlane(site);   // root all control flow in SGPRs
    if (site >= NSITES) return;

    const int oz = site % OZD;
    const int t  = site / OZD;
    const int oy = t % OYD;
    const int ox = t / OYD;
    const int ix0 = 2 * ox - 1, iy0 = 2 * oy - 1, iz0 = 2 * oz - 1;

    // Phase 1: compute the 27 neighbor flats + validity mask (all scalar).
    int flats[27];
    unsigned vmask = 0;
    {
        int j = 0;
        #pragma unroll
        for (int kx = 0; kx < 3; ++kx)
        #pragma unroll
        for (int ky = 0; ky < 3; ++ky)
        #pragma unroll
        for (int kz = 0; kz < 3; ++kz) {
            const int ix = ix0 + kx, iy = iy0 + ky, iz = iz0 + kz;
            const bool v = ((unsigned)ix < IXD) &
                           ((unsigned)iy < IYD) &
                           ((unsigned)iz < IZD);
            flats[j] = v ? (ix * IYD + iy) * IZD + iz : 0;
            vmask |= (unsigned)v << j;
            ++j;
        }
    }

    // Phase 2: batch all 27 lookups (independent scalar loads pipeline).
    int gval[27];
    #pragma unroll
    for (int q = 0; q < 27; ++q) gval[q] = g[flats[q]];

    // Phase 3: accumulate hits. All branches wave-uniform.
    float acc = 0.f;
    #pragma unroll
    for (int q = 0; q < 27; ++q) {
        if (!((vmask >> q) & 1u)) continue;
        int idx = gval[q];
        while (idx) {                         // duplicate-coord chain, avg len 1
            const int n = idx - 1;
            const float* __restrict__ fr = feat + (size_t)n * CIN;      // scalar
            const float* __restrict__ wc = weight + (size_t)q * CIN * COUT + lane;
            #pragma unroll
            for (int ci = 0; ci < CIN; ++ci)
                acc = fmaf(fr[ci], wc[(size_t)ci * COUT], acc);         // 256B coalesced w
            idx = nxt[n];
        }
    }

    out[(size_t)site * COUT + lane] = acc;    // fused zero + result, 256B coalesced
}

extern "C" void kernel_launch(void* const* d_in, const int* in_sizes, int n_in,
                              void* d_out, int out_size, void* d_ws, size_t ws_size,
                              hipStream_t stream) {
    const float* feat   = (const float*)d_in[0];
    const int*   coords = (const int*)d_in[1];
    const float* weight = (const float*)d_in[2];
    float*       out    = (float*)d_out;
    const int nnz = in_sizes[0] / CIN;       // 220939

    int* grid_idx = (int*)d_ws;                       // NCELLS ints (47.3 MB)
    int* nxt      = grid_idx + NCELLS;                // nnz ints

    zero_grid<<<NCELLS / 4 / 256 + 1, 256, 0, stream>>>(grid_idx);
    build_grid<<<(nnz + 255) / 256, 256, 0, stream>>>(coords, grid_idx, nxt, nnz);
    spconv_gather<<<NSITES / 4, 256, 0, stream>>>(feat, weight, grid_idx, nxt, out);
}

// Round 3
// 583.574 us; speedup vs baseline: 2.9962x; 2.9962x over previous
//
#include <hip/hip_runtime.h>

// SparseConv3d(32->64, k=3, s=2, p=1), (21,800,704), nnz=220939.
// Rulebook scatter: build 27 contiguous per-k (point,site) pair lists, then
// k-major scatter with W[k]'s column held in 32 VGPRs (lane = cout).
// Validity per dim (c1 = c+pad = c+1): odd c1 -> k=1; even c1 -> k=2 always,
// k=0 iff c1/2 < OD.  o = (c1-k)/2.

#define CIN  32
#define COUT 64
#define OXD  11
#define OYD  400
#define OZD  352
#define NSITES (OXD * OYD * OZD)

constexpr int CHUNKS = 96;   // blocks per k in scatter (27*96 = 2592 blocks)

__global__ __launch_bounds__(256) void zero_out_k(float4* __restrict__ out4,
                                                  int n4, int* __restrict__ gcnt) {
    const int i = blockIdx.x * 256 + threadIdx.x;
    if (i < n4) out4[i] = make_float4(0.f, 0.f, 0.f, 0.f);
    if (i < 27) gcnt[i] = 0;
}

__global__ __launch_bounds__(256) void build_pairs(
    const int* __restrict__ coords, int2* __restrict__ arena,
    int* __restrict__ gcnt, int nnz)
{
    __shared__ int lcnt[27];
    __shared__ int lbase[27];
    const int t = threadIdx.x;
    if (t < 27) lcnt[t] = 0;
    __syncthreads();

    const int n = blockIdx.x * 256 + t;
    int ncomb = 0;
    int ck[8], cls[8], csite[8];
    if (n < nnz) {
        const int cx = coords[3 * n + 0];
        const int cy = coords[3 * n + 1];
        const int cz = coords[3 * n + 2];
        int kxl[2], oxl[2], nx;
        int kyl[2], oyl[2], ny;
        int kzl[2], ozl[2], nz;
        {
            const int c1 = cx + 1;
            if (c1 & 1) { kxl[0] = 1; oxl[0] = c1 >> 1; nx = 1; }
            else { kxl[0] = 2; oxl[0] = (c1 - 2) >> 1; nx = 1;
                   if ((c1 >> 1) < OXD) { kxl[1] = 0; oxl[1] = c1 >> 1; nx = 2; } }
        }
        {
            const int c1 = cy + 1;
            if (c1 & 1) { kyl[0] = 1; oyl[0] = c1 >> 1; ny = 1; }
            else { kyl[0] = 2; oyl[0] = (c1 - 2) >> 1; ny = 1;
                   if ((c1 >> 1) < OYD) { kyl[1] = 0; oyl[1] = c1 >> 1; ny = 2; } }
        }
        {
            const int c1 = cz + 1;
            if (c1 & 1) { kzl[0] = 1; ozl[0] = c1 >> 1; nz = 1; }
            else { kzl[0] = 2; ozl[0] = (c1 - 2) >> 1; nz = 1;
                   if ((c1 >> 1) < OZD) { kzl[1] = 0; ozl[1] = c1 >> 1; nz = 2; } }
        }
        for (int ix = 0; ix < nx; ++ix)
            for (int iy = 0; iy < ny; ++iy)
                for (int iz = 0; iz < nz; ++iz) {
                    const int k = kxl[ix] * 9 + kyl[iy] * 3 + kzl[iz];
                    const int site = (oxl[ix] * OYD + oyl[iy]) * OZD + ozl[iz];
                    ck[ncomb] = k;
                    csite[ncomb] = site;
                    cls[ncomb] = atomicAdd(&lcnt[k], 1);   // LDS atomic
                    ++ncomb;
                }
    }
    __syncthreads();
    if (t < 27) lbase[t] = atomicAdd(&gcnt[t], lcnt[t]);   // 27 global atomics/block
    __syncthreads();
    for (int c = 0; c < ncomb; ++c) {
        const int k = ck[c];
        arena[(size_t)k * nnz + lbase[k] + cls[c]] = make_int2(n, csite[c]);
    }
}

__global__ __launch_bounds__(256) void spconv_scatter(
    const float* __restrict__ feat,
    const float* __restrict__ weight,
    const int2*  __restrict__ arena,
    const int*   __restrict__ gcnt,
    float*       __restrict__ out,
    int nnz)
{
    const int lane = threadIdx.x & 63;
    const int k     = blockIdx.x % 27;
    const int chunk = blockIdx.x / 27;
    const int cnt = gcnt[k];
    if (cnt == 0) return;

    // W[k] column in registers: w[ci] = W[k][ci][lane]  (coalesced preload)
    float w[CIN];
    const float* __restrict__ Wk = weight + (size_t)k * CIN * COUT;
    #pragma unroll
    for (int ci = 0; ci < CIN; ++ci) w[ci] = Wk[ci * COUT + lane];

    const int NW = CHUNKS * 4;                 // waves per k
    const int widk = chunk * 4 + (threadIdx.x >> 6);
    const int C = (cnt + NW - 1) / NW;         // pairs per wave
    const int start = widk * C;
    const int end   = min(start + C, cnt);
    const int2* __restrict__ ak = arena + (size_t)k * nnz;

    for (int i0 = start; i0 < end; i0 += 64) {
        const int take = min(64, end - i0);
        int idx = i0 + lane;
        if (idx >= end) idx = end - 1;
        const int2 pr = ak[idx];               // one coalesced 512B pair load/wave

        for (int j = 0; j < take; ++j) {
            const int pt = __builtin_amdgcn_readlane(pr.x, j);   // SGPR
            const int st = __builtin_amdgcn_readlane(pr.y, j);   // SGPR
            const float* __restrict__ fr = feat + (size_t)pt * CIN;  // scalar loads
            float a0 = 0.f, a1 = 0.f, a2 = 0.f, a3 = 0.f;
            #pragma unroll
            for (int ci = 0; ci < CIN; ci += 4) {
                a0 = fmaf(fr[ci + 0], w[ci + 0], a0);
                a1 = fmaf(fr[ci + 1], w[ci + 1], a1);
                a2 = fmaf(fr[ci + 2], w[ci + 2], a2);
                a3 = fmaf(fr[ci + 3], w[ci + 3], a3);
            }
            atomicAdd(out + (size_t)st * COUT + lane, (a0 + a1) + (a2 + a3));
        }
    }
}

extern "C" void kernel_launch(void* const* d_in, const int* in_sizes, int n_in,
                              void* d_out, int out_size, void* d_ws, size_t ws_size,
                              hipStream_t stream) {
    const float* feat   = (const float*)d_in[0];
    const int*   coords = (const int*)d_in[1];
    const float* weight = (const float*)d_in[2];
    float*       out    = (float*)d_out;
    const int nnz = in_sizes[0] / CIN;         // 220939

    int2* arena = (int2*)d_ws;                  // 27 * nnz int2  (47.7 MB)
    int*  gcnt  = (int*)(arena + (size_t)27 * nnz);   // 27 ints

    const int n4 = out_size / 4;                // exact (99,123,200 / 4)
    zero_out_k<<<(n4 + 255) / 256, 256, 0, stream>>>((float4*)out, n4, gcnt);
    build_pairs<<<(nnz + 255) / 256, 256, 0, stream>>>(coords, arena, gcnt, nnz);
    spconv_scatter<<<27 * CHUNKS, 256, 0, stream>>>(feat, weight, arena, gcnt, out, nnz);
}

// Round 4
// 570.943 us; speedup vs baseline: 3.0624x; 1.0221x over previous
//
#include <hip/hip_runtime.h>

// SparseConv3d(32->64, k=3, s=2, p=1), (21,800,704), nnz=220939.
// Rulebook scatter, round 4: per-wave 64-pair LDS tiles.
//  - build 27 contiguous per-k (point,site) pair lists (parity rule)
//  - scatter: wave loads 64 pairs coalesced, vector-stages their feat rows
//    into a private LDS tile, then per pair: 8 broadcast ds_read_b128 +
//    16 v_pk_fma_f32 (weights in VGPRs, lane = cout), 1 atomicAdd.

#define CIN  32
#define COUT 64
#define OXD  11
#define OYD  400
#define OZD  352

constexpr int CHUNKS = 96;   // blocks per k in scatter (27*96 = 2592 blocks)

typedef float v2f __attribute__((ext_vector_type(2)));

__global__ __launch_bounds__(256) void zero_out_k(float4* __restrict__ out4,
                                                  int n4, int* __restrict__ gcnt) {
    const int i = blockIdx.x * 256 + threadIdx.x;
    if (i < n4) out4[i] = make_float4(0.f, 0.f, 0.f, 0.f);
    if (i < 27) gcnt[i] = 0;
}

__global__ __launch_bounds__(256) void build_pairs(
    const int* __restrict__ coords, int2* __restrict__ arena,
    int* __restrict__ gcnt, int nnz)
{
    __shared__ int lcnt[27];
    __shared__ int lbase[27];
    const int t = threadIdx.x;
    if (t < 27) lcnt[t] = 0;
    __syncthreads();

    const int n = blockIdx.x * 256 + t;
    int ncomb = 0;
    int ck[8], cls[8], csite[8];
    if (n < nnz) {
        const int cx = coords[3 * n + 0];
        const int cy = coords[3 * n + 1];
        const int cz = coords[3 * n + 2];
        int kxl[2], oxl[2], nx;
        int kyl[2], oyl[2], ny;
        int kzl[2], ozl[2], nz;
        {
            const int c1 = cx + 1;
            if (c1 & 1) { kxl[0] = 1; oxl[0] = c1 >> 1; nx = 1; }
            else { kxl[0] = 2; oxl[0] = (c1 - 2) >> 1; nx = 1;
                   if ((c1 >> 1) < OXD) { kxl[1] = 0; oxl[1] = c1 >> 1; nx = 2; } }
        }
        {
            const int c1 = cy + 1;
            if (c1 & 1) { kyl[0] = 1; oyl[0] = c1 >> 1; ny = 1; }
            else { kyl[0] = 2; oyl[0] = (c1 - 2) >> 1; ny = 1;
                   if ((c1 >> 1) < OYD) { kyl[1] = 0; oyl[1] = c1 >> 1; ny = 2; } }
        }
        {
            const int c1 = cz + 1;
            if (c1 & 1) { kzl[0] = 1; ozl[0] = c1 >> 1; nz = 1; }
            else { kzl[0] = 2; ozl[0] = (c1 - 2) >> 1; nz = 1;
                   if ((c1 >> 1) < OZD) { kzl[1] = 0; ozl[1] = c1 >> 1; nz = 2; } }
        }
        for (int ix = 0; ix < nx; ++ix)
            for (int iy = 0; iy < ny; ++iy)
                for (int iz = 0; iz < nz; ++iz) {
                    const int k = kxl[ix] * 9 + kyl[iy] * 3 + kzl[iz];
                    const int site = (oxl[ix] * OYD + oyl[iy]) * OZD + ozl[iz];
                    ck[ncomb] = k;
                    csite[ncomb] = site;
                    cls[ncomb] = atomicAdd(&lcnt[k], 1);
                    ++ncomb;
                }
    }
    __syncthreads();
    if (t < 27) lbase[t] = atomicAdd(&gcnt[t], lcnt[t]);
    __syncthreads();
    for (int c = 0; c < ncomb; ++c) {
        const int k = ck[c];
        arena[(size_t)k * nnz + lbase[k] + cls[c]] = make_int2(n, csite[c]);
    }
}

__global__ __launch_bounds__(256) void spconv_scatter(
    const float* __restrict__ feat,
    const float* __restrict__ weight,
    const int2*  __restrict__ arena,
    const int*   __restrict__ gcnt,
    float*       __restrict__ out,
    int nnz)
{
    // [wave][b][pair][4] : per-wave 8KB tile of 64 feat rows, split into
    // 8 float4 blocks. ds_write is contiguous 1KB per instr; reads per pair
    // are wave-uniform (broadcast, conflict-free).
    __shared__ float lds[4][8][64][4];   // 32 KB

    const int lane = threadIdx.x & 63;
    const int wid  = threadIdx.x >> 6;
    const int k     = blockIdx.x % 27;
    const int chunk = blockIdx.x / 27;
    const int cnt = gcnt[k];
    if (cnt == 0) return;

    // W[k] column in registers as float2 pairs: w2[i] = W[k][2i..2i+1][lane]
    v2f w2[16];
    const float* __restrict__ Wk = weight + (size_t)k * CIN * COUT;
    #pragma unroll
    for (int i = 0; i < 16; ++i) {
        w2[i][0] = Wk[(2 * i + 0) * COUT + lane];
        w2[i][1] = Wk[(2 * i + 1) * COUT + lane];
    }

    const int NW = CHUNKS * 4;
    const int widk = chunk * 4 + wid;
    const int C = (cnt + NW - 1) / NW;
    const int start = widk * C;
    const int end   = min(start + C, cnt);
    const int2* __restrict__ ak = arena + (size_t)k * nnz;
    float* __restrict__ outl = out + lane;

    for (int i0 = start; i0 < end; i0 += 64) {
        const int take = min(64, end - i0);
        const int idx = min(i0 + lane, end - 1);
        const int2 pr = ak[idx];                       // coalesced 512B pair load

        // Stage 64 feat rows: 8 independent float4 loads/lane (latency
        // amortized over the whole tile), then 8 contiguous ds_write_b128.
        const float4* __restrict__ fr4 = (const float4*)(feat + (size_t)pr.x * CIN);
        float4 r[8];
        #pragma unroll
        for (int b = 0; b < 8; ++b) r[b] = fr4[b];
        #pragma unroll
        for (int b = 0; b < 8; ++b) *(float4*)&lds[wid][b][lane][0] = r[b];
        asm volatile("s_waitcnt lgkmcnt(0)" ::: "memory");  // wave-private tile: no barrier

        for (int j = 0; j < take; ++j) {
            v2f a0 = {0.f, 0.f}, a1 = {0.f, 0.f};
            #pragma unroll
            for (int b = 0; b < 8; ++b) {
                const float4 f = *(const float4*)&lds[wid][b][j][0];  // broadcast
                v2f f01 = {f.x, f.y};
                v2f f23 = {f.z, f.w};
#if __has_builtin(__builtin_elementwise_fma)
                a0 = __builtin_elementwise_fma(f01, w2[2 * b + 0], a0);
                a1 = __builtin_elementwise_fma(f23, w2[2 * b + 1], a1);
#else
                a0[0] = fmaf(f01[0], w2[2 * b + 0][0], a0[0]);
                a0[1] = fmaf(f01[1], w2[2 * b + 0][1], a0[1]);
                a1[0] = fmaf(f23[0], w2[2 * b + 1][0], a1[0]);
                a1[1] = fmaf(f23[1], w2[2 * b + 1][1], a1[1]);
#endif
            }
            const int st = __builtin_amdgcn_readlane(pr.y, j);      // SGPR site
            const float acc = (a0[0] + a0[1]) + (a1[0] + a1[1]);
            atomicAdd(outl + (size_t)st * COUT, acc);               // no-return atomic
        }
    }
}

extern "C" void kernel_launch(void* const* d_in, const int* in_sizes, int n_in,
                              void* d_out, int out_size, void* d_ws, size_t ws_size,
                              hipStream_t stream) {
    const float* feat   = (const float*)d_in[0];
    const int*   coords = (const int*)d_in[1];
    const float* weight = (const float*)d_in[2];
    float*       out    = (float*)d_out;
    const int nnz = in_sizes[0] / CIN;         // 220939

    int2* arena = (int2*)d_ws;                        // 27 * nnz int2 (47.7 MB)
    int*  gcnt  = (int*)(arena + (size_t)27 * nnz);   // 27 ints

    const int n4 = out_size / 4;               // exact (99,123,200 / 4)
    zero_out_k<<<(n4 + 255) / 256, 256, 0, stream>>>((float4*)out, n4, gcnt);
    build_pairs<<<(nnz + 255) / 256, 256, 0, stream>>>(coords, arena, gcnt, nnz);
    spconv_scatter<<<27 * CHUNKS, 256, 0, stream>>>(feat, weight, arena, gcnt, out, nnz);
}